// Round 2
// baseline (5314.877 us; speedup 1.0000x reference)
//
#include <hip/hip_runtime.h>

typedef unsigned short u16;
typedef unsigned int   u32;

// Problem dims (hardcoded per reference shape_source)
constexpr int Bc  = 4;
constexpr int Nc  = 8192;
constexpr int Hc  = 16;
constexpr int DHc = 64;
constexpr int HD  = Hc * DHc;   // 1024
constexpr int BN  = Bc * Nc;    // 32768

// ---------------- bf16 helpers ----------------
__device__ __forceinline__ float bf2f(u32 lo16) {
    return __uint_as_float(lo16 << 16);
}
__device__ __forceinline__ u16 f2bf(float f) {
    u32 u = __float_as_uint(f);
    u += 0x7fffu + ((u >> 16) & 1u);   // round-to-nearest-even
    return (u16)(u >> 16);
}
__device__ __forceinline__ void unpack8(uint4 r, float* d) {
    d[0] = bf2f(r.x & 0xffffu); d[1] = bf2f(r.x >> 16);
    d[2] = bf2f(r.y & 0xffffu); d[3] = bf2f(r.y >> 16);
    d[4] = bf2f(r.z & 0xffffu); d[5] = bf2f(r.z >> 16);
    d[6] = bf2f(r.w & 0xffffu); d[7] = bf2f(r.w >> 16);
}
__device__ __forceinline__ u32 pack2(float a, float b) {
    return (u32)f2bf(a) | ((u32)f2bf(b) << 16);
}

// ---------------------------------------------------------------------------
// GEMM: out_bf16[M=32768,1024] = (X[M,1024] @ W[1024,1024]) * scale + bias,
// then optional per-row int mask. 128x128 tile, 256 thr, 8x8/thread, K=32.
// ---------------------------------------------------------------------------
__global__ __launch_bounds__(256) void proj_gemm(
    const float* __restrict__ X, const float* __restrict__ W,
    const float* __restrict__ bias, const int* __restrict__ maskI,
    u16* __restrict__ outp, float scale)
{
    __shared__ float As[32][132];   // As[k][m] (transposed)
    __shared__ float Bs[32][132];   // Bs[k][n]
    const int t  = threadIdx.x;
    const int cb = blockIdx.x * 128;
    const int rb = blockIdx.y * 128;
    const int tx = t & 15, ty = t >> 4;

    float acc[8][8];
#pragma unroll
    for (int i = 0; i < 8; ++i)
#pragma unroll
        for (int j = 0; j < 8; ++j) acc[i][j] = 0.f;

    for (int k0 = 0; k0 < 1024; k0 += 32) {
#pragma unroll
        for (int it = 0; it < 4; ++it) {
            int f = t + 256 * it;
            int r = f >> 3, c4 = f & 7;
            float4 a = *(const float4*)&X[(size_t)(rb + r) * 1024 + k0 + c4 * 4];
            As[c4 * 4 + 0][r] = a.x;
            As[c4 * 4 + 1][r] = a.y;
            As[c4 * 4 + 2][r] = a.z;
            As[c4 * 4 + 3][r] = a.w;
        }
#pragma unroll
        for (int it = 0; it < 4; ++it) {
            int f = t + 256 * it;
            int r = f >> 5, c4 = f & 31;
            *(float4*)&Bs[r][c4 * 4] =
                *(const float4*)&W[(size_t)(k0 + r) * 1024 + cb + c4 * 4];
        }
        __syncthreads();
#pragma unroll
        for (int kk = 0; kk < 32; ++kk) {
            float4 a0 = *(const float4*)&As[kk][ty * 4];
            float4 a1 = *(const float4*)&As[kk][64 + ty * 4];
            float4 b0 = *(const float4*)&Bs[kk][tx * 4];
            float4 b1 = *(const float4*)&Bs[kk][64 + tx * 4];
            float av[8] = {a0.x, a0.y, a0.z, a0.w, a1.x, a1.y, a1.z, a1.w};
            float bv[8] = {b0.x, b0.y, b0.z, b0.w, b1.x, b1.y, b1.z, b1.w};
#pragma unroll
            for (int i = 0; i < 8; ++i)
#pragma unroll
                for (int j = 0; j < 8; ++j) acc[i][j] += av[i] * bv[j];
        }
        __syncthreads();
    }

    const float4 bias0 = *(const float4*)&bias[cb + tx * 4];
    const float4 bias1 = *(const float4*)&bias[cb + 64 + tx * 4];
#pragma unroll
    for (int half = 0; half < 2; ++half) {
#pragma unroll
        for (int i = 0; i < 4; ++i) {
            int row = rb + half * 64 + ty * 4 + i;
            int ai  = half * 4 + i;
            float mrow = maskI ? (float)maskI[row] : 1.f;
            ushort4 o0, o1;
            o0.x = f2bf((acc[ai][0] * scale + bias0.x) * mrow);
            o0.y = f2bf((acc[ai][1] * scale + bias0.y) * mrow);
            o0.z = f2bf((acc[ai][2] * scale + bias0.z) * mrow);
            o0.w = f2bf((acc[ai][3] * scale + bias0.w) * mrow);
            o1.x = f2bf((acc[ai][4] * scale + bias1.x) * mrow);
            o1.y = f2bf((acc[ai][5] * scale + bias1.y) * mrow);
            o1.z = f2bf((acc[ai][6] * scale + bias1.z) * mrow);
            o1.w = f2bf((acc[ai][7] * scale + bias1.w) * mrow);
            *(ushort4*)(outp + (size_t)row * 1024 + cb + tx * 4)      = o0;
            *(ushort4*)(outp + (size_t)row * 1024 + cb + 64 + tx * 4) = o1;
        }
    }
}

// ---------------------------------------------------------------------------
// Final GEMM: fp32 out = X_bf16[32768,1024] @ Wo[1024,1024] + bo
// ---------------------------------------------------------------------------
__global__ __launch_bounds__(256) void gemm_bf16A(
    const u16* __restrict__ X, const float* __restrict__ W,
    const float* __restrict__ bias, float* __restrict__ outp)
{
    __shared__ float As[32][132];
    __shared__ float Bs[32][132];
    const int t  = threadIdx.x;
    const int cb = blockIdx.x * 128;
    const int rb = blockIdx.y * 128;
    const int tx = t & 15, ty = t >> 4;

    float acc[8][8];
#pragma unroll
    for (int i = 0; i < 8; ++i)
#pragma unroll
        for (int j = 0; j < 8; ++j) acc[i][j] = 0.f;

    for (int k0 = 0; k0 < 1024; k0 += 32) {
#pragma unroll
        for (int it = 0; it < 2; ++it) {
            int f = t + 256 * it;            // [0,512): 128 rows x 4 chunks
            int r = f >> 2, c8 = f & 3;
            uint4 raw = *(const uint4*)(X + (size_t)(rb + r) * 1024 + k0 + c8 * 8);
            float v[8]; unpack8(raw, v);
#pragma unroll
            for (int e = 0; e < 8; ++e) As[c8 * 8 + e][r] = v[e];
        }
#pragma unroll
        for (int it = 0; it < 4; ++it) {
            int f = t + 256 * it;
            int r = f >> 5, c4 = f & 31;
            *(float4*)&Bs[r][c4 * 4] =
                *(const float4*)&W[(size_t)(k0 + r) * 1024 + cb + c4 * 4];
        }
        __syncthreads();
#pragma unroll
        for (int kk = 0; kk < 32; ++kk) {
            float4 a0 = *(const float4*)&As[kk][ty * 4];
            float4 a1 = *(const float4*)&As[kk][64 + ty * 4];
            float4 b0 = *(const float4*)&Bs[kk][tx * 4];
            float4 b1 = *(const float4*)&Bs[kk][64 + tx * 4];
            float av[8] = {a0.x, a0.y, a0.z, a0.w, a1.x, a1.y, a1.z, a1.w};
            float bv[8] = {b0.x, b0.y, b0.z, b0.w, b1.x, b1.y, b1.z, b1.w};
#pragma unroll
            for (int i = 0; i < 8; ++i)
#pragma unroll
                for (int j = 0; j < 8; ++j) acc[i][j] += av[i] * bv[j];
        }
        __syncthreads();
    }

    const float4 bias0 = *(const float4*)&bias[cb + tx * 4];
    const float4 bias1 = *(const float4*)&bias[cb + 64 + tx * 4];
#pragma unroll
    for (int half = 0; half < 2; ++half) {
#pragma unroll
        for (int i = 0; i < 4; ++i) {
            int row = rb + half * 64 + ty * 4 + i;
            int ai  = half * 4 + i;
            float4 o0, o1;
            o0.x = acc[ai][0] + bias0.x; o0.y = acc[ai][1] + bias0.y;
            o0.z = acc[ai][2] + bias0.z; o0.w = acc[ai][3] + bias0.w;
            o1.x = acc[ai][4] + bias1.x; o1.y = acc[ai][5] + bias1.y;
            o1.z = acc[ai][6] + bias1.z; o1.w = acc[ai][7] + bias1.w;
            *(float4*)&outp[(size_t)row * 1024 + cb + tx * 4]      = o0;
            *(float4*)&outp[(size_t)row * 1024 + cb + 64 + tx * 4] = o1;
        }
    }
}

// ---------------------------------------------------------------------------
__global__ void mask_to_float(const int* __restrict__ mi, float* __restrict__ mo)
{
    int i = blockIdx.x * 256 + threadIdx.x;
    if (i < BN) mo[i] = (float)mi[i];
}

__global__ void sentinel_fill(float* __restrict__ o, int n)
{
    int i = blockIdx.x * 256 + threadIdx.x;
    if (i < n) o[i] = 12345.0f;
}

// ---------------------------------------------------------------------------
// avg-pool-2 along seq for bf16 q,k,v (grid.y 0..2) and fp32 mask (grid.y 3).
// nRows = B * nl_out. grid.x = nRows/2 blocks of 256 (one 8-elem chunk each).
// ---------------------------------------------------------------------------
__global__ __launch_bounds__(256) void pool_level(
    const u16* __restrict__ qi, u16* __restrict__ qo,
    const u16* __restrict__ ki, u16* __restrict__ ko,
    const u16* __restrict__ vi, u16* __restrict__ vo,
    const float* __restrict__ mi, float* __restrict__ mo, int nRows)
{
    int idx = blockIdx.x * 256 + threadIdx.x;
    int y   = blockIdx.y;
    if (y == 3) {
        if (idx < nRows) mo[idx] = 0.5f * (mi[2 * idx] + mi[2 * idx + 1]);
        return;
    }
    const u16* in  = (y == 0) ? qi : (y == 1) ? ki : vi;
    u16*       out = (y == 0) ? qo : (y == 1) ? ko : vo;
    int r = idx >> 7, c8 = idx & 127;     // 128 chunks of 8 per 1024-row
    uint4 a = *(const uint4*)(in + (size_t)(2 * r) * 1024 + c8 * 8);
    uint4 b = *(const uint4*)(in + (size_t)(2 * r + 1) * 1024 + c8 * 8);
    float fa[8], fb[8];
    unpack8(a, fa); unpack8(b, fb);
    uint4 o;
    o.x = pack2(0.5f * (fa[0] + fb[0]), 0.5f * (fa[1] + fb[1]));
    o.y = pack2(0.5f * (fa[2] + fb[2]), 0.5f * (fa[3] + fb[3]));
    o.z = pack2(0.5f * (fa[4] + fb[4]), 0.5f * (fa[5] + fb[5]));
    o.w = pack2(0.5f * (fa[6] + fb[6]), 0.5f * (fa[7] + fb[7]));
    *(uint4*)(out + (size_t)r * 1024 + c8 * 8) = o;
}

// ---------------------------------------------------------------------------
// One level of hierarchical block attention. WG = (block, head, batch).
// q block [32,64]; window [96,64] (zero-padded outside [0,nl)).
// num accumulates into full-res d_out with repeat 2^lvl (= at lvl0, += else).
// ---------------------------------------------------------------------------
__global__ __launch_bounds__(256) void attn_level(
    const u16* __restrict__ q, const u16* __restrict__ k,
    const u16* __restrict__ v, const float* __restrict__ m,
    const float* __restrict__ rpbL,
    float* __restrict__ num, float* __restrict__ den, int nl, int lvl)
{
    __shared__ float qs[32][68];
    __shared__ float kvs[96][68];
    __shared__ float wT[96][36];   // wT[j][i]
    __shared__ float rps[128];
    __shared__ float mw[96];

    const int t   = threadIdx.x;
    const int blk = blockIdx.x, h = blockIdx.y, b = blockIdx.z;
    const size_t baseRow = (size_t)b * nl + blk * 32;
    const int wbase = blk * 32 - 32;

    // stage q: 32 rows x 8 chunks = 256 items
    {
        int r = t >> 3, c8 = t & 7;
        uint4 raw = *(const uint4*)(q + (baseRow + r) * 1024 + h * 64 + c8 * 8);
        float vv[8]; unpack8(raw, vv);
#pragma unroll
        for (int e = 0; e < 8; ++e) qs[r][c8 * 8 + e] = vv[e];
    }
    // stage k window: 96 rows x 8 chunks = 768 items
#pragma unroll
    for (int it = 0; it < 3; ++it) {
        int f = t + 256 * it;
        int r = f >> 3, c8 = f & 7;
        int wp = wbase + r;
        float vv[8] = {0.f, 0.f, 0.f, 0.f, 0.f, 0.f, 0.f, 0.f};
        if (wp >= 0 && wp < nl) {
            uint4 raw = *(const uint4*)(k + ((size_t)b * nl + wp) * 1024 + h * 64 + c8 * 8);
            unpack8(raw, vv);
        }
#pragma unroll
        for (int e = 0; e < 8; ++e) kvs[r][c8 * 8 + e] = vv[e];
    }
    if (t < 96) {
        int wp = wbase + t;
        mw[t] = (wp >= 0 && wp < nl) ? m[b * nl + wp] : 0.f;
    }
    if (t < 127) rps[t] = rpbL[h * 127 + t];
    __syncthreads();

    // phase 1: logits 4(i) x 3(j) per thread
    const int ti = t & 7, tj = t >> 3;
    float lg[4][3];
#pragma unroll
    for (int ii = 0; ii < 4; ++ii)
#pragma unroll
        for (int jj = 0; jj < 3; ++jj) lg[ii][jj] = 0.f;

#pragma unroll
    for (int d4 = 0; d4 < 16; ++d4) {
        float4 kf[3];
#pragma unroll
        for (int jj = 0; jj < 3; ++jj)
            kf[jj] = *(const float4*)&kvs[tj * 3 + jj][d4 * 4];
#pragma unroll
        for (int ii = 0; ii < 4; ++ii) {
            float4 a = *(const float4*)&qs[ti * 4 + ii][d4 * 4];
#pragma unroll
            for (int jj = 0; jj < 3; ++jj)
                lg[ii][jj] += a.x * kf[jj].x + a.y * kf[jj].y +
                              a.z * kf[jj].z + a.w * kf[jj].w;
        }
    }
#pragma unroll
    for (int ii = 0; ii < 4; ++ii) {
        int i = ti * 4 + ii;
#pragma unroll
        for (int jj = 0; jj < 3; ++jj) {
            int j = tj * 3 + jj;
            float w = __expf(lg[ii][jj] + rps[j - i + 31]) * mw[j];
            if (lvl > 0) {
                int bj = j >> 5, pl = j & 31;
                bool inv = (bj == 1) ||
                           (bj == 0 && i < 16 && pl >= 16) ||
                           (bj == 2 && i >= 16 && pl < 16);
                if (inv) w = 0.f;
            }
            wT[j][i] = w;
        }
    }
    __syncthreads();

    // stage v window into kvs
#pragma unroll
    for (int it = 0; it < 3; ++it) {
        int f = t + 256 * it;
        int r = f >> 3, c8 = f & 7;
        int wp = wbase + r;
        float vv[8] = {0.f, 0.f, 0.f, 0.f, 0.f, 0.f, 0.f, 0.f};
        if (wp >= 0 && wp < nl) {
            uint4 raw = *(const uint4*)(v + ((size_t)b * nl + wp) * 1024 + h * 64 + c8 * 8);
            unpack8(raw, vv);
        }
#pragma unroll
        for (int e = 0; e < 8; ++e) kvs[r][c8 * 8 + e] = vv[e];
    }
    __syncthreads();

    // phase 2: num_l = w @ vw; rows {2*i2, 2*i2+1}, dims dg*4..+3
    const int i2 = t >> 4, dg = t & 15;
    float4 acc0 = make_float4(0.f, 0.f, 0.f, 0.f);
    float4 acc1 = make_float4(0.f, 0.f, 0.f, 0.f);
#pragma unroll 8
    for (int j = 0; j < 96; ++j) {
        float4 vv = *(const float4*)&kvs[j][dg * 4];
        float w0 = wT[j][2 * i2];
        float w1 = wT[j][2 * i2 + 1];
        acc0.x += w0 * vv.x; acc0.y += w0 * vv.y;
        acc0.z += w0 * vv.z; acc0.w += w0 * vv.w;
        acc1.x += w1 * vv.x; acc1.y += w1 * vv.y;
        acc1.z += w1 * vv.z; acc1.w += w1 * vv.w;
    }

    // accumulate into full-res num with repeat 2^lvl
    const int rr = 1 << lvl;
    const int cn0 = blk * 32 + 2 * i2;
    size_t base0 = ((size_t)b * Nc + (size_t)cn0 * rr) * 1024 + h * 64 + dg * 4;
    size_t base1 = base0 + (size_t)rr * 1024;
    if (lvl == 0) {
        *(float4*)&num[base0] = acc0;
        *(float4*)&num[base1] = acc1;
    } else {
        for (int rep = 0; rep < rr; ++rep) {
            float4 o0 = *(const float4*)&num[base0 + (size_t)rep * 1024];
            o0.x += acc0.x; o0.y += acc0.y; o0.z += acc0.z; o0.w += acc0.w;
            *(float4*)&num[base0 + (size_t)rep * 1024] = o0;
            float4 o1 = *(const float4*)&num[base1 + (size_t)rep * 1024];
            o1.x += acc1.x; o1.y += acc1.y; o1.z += acc1.z; o1.w += acc1.w;
            *(float4*)&num[base1 + (size_t)rep * 1024] = o1;
        }
    }

    if (t < 32) {
        float s = 0.f;
#pragma unroll 16
        for (int j = 0; j < 96; ++j) s += wT[j][t];
        const int cn = blk * 32 + t;
        size_t db = ((size_t)b * Nc + (size_t)cn * rr) * 16 + h;
        if (lvl == 0) {
            den[db] = s;
        } else {
            for (int rep = 0; rep < rr; ++rep) den[db + (size_t)rep * 16] += s;
        }
    }
}

// ---------------------------------------------------------------------------
// combine: pre_bf16 = num / (den + 1e-9) * qmask
// ---------------------------------------------------------------------------
__global__ __launch_bounds__(256) void combine_kernel(
    const float* __restrict__ num, const float* __restrict__ den,
    const int* __restrict__ qmask, u16* __restrict__ pre)
{
    int idx = blockIdx.x * 256 + threadIdx.x;   // f4 index over [BN, 256]
    int row = idx >> 8, c4 = idx & 255;
    int h = c4 >> 4;
    float4 ns = *(const float4*)&num[(size_t)row * 1024 + c4 * 4];
    float f = (float)qmask[row] / (den[(size_t)row * 16 + h] + 1e-9f);
    ushort4 o;
    o.x = f2bf(ns.x * f); o.y = f2bf(ns.y * f);
    o.z = f2bf(ns.z * f); o.w = f2bf(ns.w * f);
    *(ushort4*)(pre + (size_t)row * 1024 + c4 * 4) = o;
}

// ---------------------------------------------------------------------------
extern "C" void kernel_launch(void* const* d_in, const int* in_sizes, int n_in,
                              void* d_out, int out_size, void* d_ws, size_t ws_size,
                              hipStream_t stream)
{
    const float* Xq    = (const float*)d_in[0];
    const float* Xkv   = (const float*)d_in[1];
    const int*   qmask = (const int*)d_in[2];
    const int*   kmask = (const int*)d_in[3];
    const float* Wq    = (const float*)d_in[4];
    const float* bq    = (const float*)d_in[5];
    const float* Wk    = (const float*)d_in[6];
    const float* bk    = (const float*)d_in[7];
    const float* Wv    = (const float*)d_in[8];
    const float* bv    = (const float*)d_in[9];
    const float* Wo    = (const float*)d_in[10];
    const float* bo    = (const float*)d_in[11];
    const float* rpb   = (const float*)d_in[12];

    // workspace layout (bf16 pyramids; num accumulator lives in d_out)
    const size_t szA = (size_t)BN * HD * 2;   // 67,108,864
    const size_t szB = szA / 2;
    const size_t needed = 3 * (szA + szB) + (size_t)BN * 6 + (size_t)BN * 16 * 4;
    if (ws_size < needed) {
        sentinel_fill<<<(out_size + 255) / 256, 256, 0, stream>>>((float*)d_out, out_size);
        return;
    }

    char* p = (char*)d_ws;
    u16* qA = (u16*)p; p += szA;
    u16* qB = (u16*)p; p += szB;
    u16* kA = (u16*)p; p += szA;
    u16* kB = (u16*)p; p += szB;
    u16* vA = (u16*)p; p += szA;
    u16* vB = (u16*)p; p += szB;
    float* mA  = (float*)p; p += (size_t)BN * 4;
    float* mB  = (float*)p; p += (size_t)BN * 2;
    float* den = (float*)p;
    float* num = (float*)d_out;

    dim3 gemmGrid(8, 256);   // 1024/128 cols, 32768/128 rows
    proj_gemm<<<gemmGrid, 256, 0, stream>>>(Xq,  Wq, bq, nullptr, qA, 0.125f);
    proj_gemm<<<gemmGrid, 256, 0, stream>>>(Xkv, Wk, bk, nullptr, kA, 1.f);
    proj_gemm<<<gemmGrid, 256, 0, stream>>>(Xkv, Wv, bv, kmask,  vA, 1.f);
    mask_to_float<<<BN / 256, 256, 0, stream>>>(kmask, mA);

    u16* qc = qA; u16* kc = kA; u16* vc = vA; float* mc = mA;
    u16* qn = qB; u16* kn = kB; u16* vn = vB; float* mn = mB;
    for (int lvl = 0; lvl < 8; ++lvl) {
        int nl = Nc >> lvl, nb = nl / 32;
        attn_level<<<dim3(nb, 16, 4), 256, 0, stream>>>(
            qc, kc, vc, mc, rpb + (size_t)lvl * Hc * 127, num, den, nl, lvl);
        if (lvl < 7) {
            int nRows = Bc * (nl / 2);
            pool_level<<<dim3(nRows / 2, 4), 256, 0, stream>>>(
                qc, qn, kc, kn, vc, vn, mc, mn, nRows);
            u16* tp;
            tp = qc; qc = qn; qn = tp;
            tp = kc; kc = kn; kn = tp;
            tp = vc; vc = vn; vn = tp;
            float* tf = mc; mc = mn; mn = tf;
        }
    }

    // pre (bf16) into qA (dead after last level), then final projection
    combine_kernel<<<BN, 256, 0, stream>>>(num, den, qmask, qA);
    gemm_bf16A<<<gemmGrid, 256, 0, stream>>>(qA, Wo, bo, (float*)d_out);
}